// Round 9
// baseline (1011.111 us; speedup 1.0000x reference)
//
#include <hip/hip_runtime.h>
#include <hip/hip_bf16.h>
#include <cstddef>

typedef __hip_bfloat16 bf;
typedef __attribute__((ext_vector_type(8))) short short8x;
typedef __attribute__((ext_vector_type(4))) float f32x4;

__device__ __forceinline__ float ldv(const float* p){ return *p; }
__device__ __forceinline__ float ldv(const bf* p){ return __bfloat162float(*p); }
__device__ __forceinline__ void stv(float* p, float v){ *p = v; }
__device__ __forceinline__ void stv(bf* p, float v){ *p = __float2bfloat16(v); }
__device__ __forceinline__ float sigm(float x){ return 1.f/(1.f + __expf(-x)); }
__device__ __forceinline__ short bfbits(float v){
  __hip_bfloat16 h = __float2bfloat16(v);
  return *(short*)&h;
}

__device__ __forceinline__ float ldin(const void* p, long i, int f32){
  return f32 ? ((const float*)p)[i] : __bfloat162float(((const bf*)p)[i]);
}

template<int K>
__device__ __forceinline__ int rot_src(int r, int t){
  int u = t / K, v = t % K;
  int s1 = v*K + (K-1-u);
  int s2 = (K-1-u)*K + (K-1-v);
  int s3 = (K-1-v)*K + u;
  return r==0 ? t : (r==1 ? s1 : (r==2 ? s2 : s3));
}

// ---------------- dtype detection ----------------
__global__ void k_detect(const void* x, int* ctrl){
  int lane = threadIdx.x;
  float mx = 0.f;
  for (int i = lane; i < 2048; i += 64){
    float v = __bfloat162float(((const bf*)x)[i]);
    if (v != v) v = 1e30f;
    mx = fmaxf(mx, fabsf(v));
  }
  #pragma unroll
  for (int off = 32; off > 0; off >>= 1) mx = fmaxf(mx, __shfl_xor(mx, off));
  if (lane == 0) ctrl[0] = (mx > 1e6f) ? 1 : 0;
}

// ---------------- build MFMA B-frag buffers for conv2/3/4 weights ----------------
__global__ __launch_bounds__(256) void k_build_bt(const void* c2, const void* c3, const void* c4,
                                                  const int* __restrict__ ctrl, short* __restrict__ btg){
  const void* ws[3] = {c2, c3, c4};
  const void* cw = ws[blockIdx.x];
  short* outp = btg + blockIdx.x * 17280;
  int f32 = ctrl[0];
  for (int i = threadIdx.x; i < 17280; i += 256){
    int t, n, k;
    if (i < 13824){
      t = i / 1536;
      int rem = i % 1536;
      int kq = rem / 384;
      n = (rem >> 3) % 48;
      k = kq*8 + (i & 7);
    } else {
      int j = i - 13824;
      t = j / 384;
      n = (j >> 3) % 48;
      k = 32 + (j & 7);
    }
    float v = 0.f;
    if (n < 40 && k < 40){
      int o = n >> 2, r = n & 3, ci = k >> 2, s = k & 3;
      v = ldin(cw, ((o*10 + ci)*4 + ((s - r) & 3))*9 + rot_src<3>(r, t), f32);
    }
    outp[i] = bfbits(v);
  }
}

// ---------------- L1 fused: att1 gate + xa write + conv1 bn1-stats ----------------
__global__ __launch_bounds__(256) void k_l1(const void* __restrict__ x,
                                            const void* __restrict__ a1,
                                            const void* __restrict__ c1,
                                            const int* __restrict__ ctrl,
                                            float* __restrict__ xa,
                                            float* __restrict__ ssum, float* __restrict__ ssq){
  __shared__ float xs[784];
  __shared__ float ws[49];
  __shared__ float xg[28*29];
  __shared__ float wr1[360];
  __shared__ float lsum[16], lss[16];
  int b = blockIdx.x, tid = threadIdx.x;
  int f32 = ctrl[0];
  for (int i = tid; i < 784; i += 256) xs[i] = ldin(x, (long)b*784 + i, f32);
  if (tid < 49) ws[tid] = ldin(a1, tid, f32) + ldin(a1, 49 + tid, f32);
  for (int i = tid; i < 360; i += 256){
    int r = i / 90, rem = i % 90, o = rem / 9, t = rem % 9;
    wr1[i] = ldin(c1, o*9 + rot_src<3>(r, t), f32);
  }
  if (tid < 16){ lsum[tid] = 0.f; lss[tid] = 0.f; }
  __syncthreads();
  for (int p = tid; p < 784; p += 256){
    int h = p / 28, w = p % 28;
    float acc = 0.f;
    #pragma unroll
    for (int u = 0; u < 7; ++u){
      int hh = h + u - 3;
      if (hh < 0 || hh >= 28) continue;
      #pragma unroll
      for (int v = 0; v < 7; ++v){
        int ww = w + v - 3;
        if (ww < 0 || ww >= 28) continue;
        acc = fmaf(xs[hh*28 + ww], ws[u*7 + v], acc);
      }
    }
    float g = xs[p] * sigm(acc);
    xg[h*29 + w] = g;
    xa[(size_t)b*784 + p] = g;
  }
  __syncthreads();
  for (int it = tid; it < 1040; it += 256){
    int o = it / 104, rem = it % 104, r = rem / 26, h = rem % 26;
    float wt[9];
    #pragma unroll
    for (int t = 0; t < 9; ++t) wt[t] = wr1[(r*10 + o)*9 + t];
    float acc[26];
    #pragma unroll
    for (int w = 0; w < 26; ++w) acc[w] = 0.f;
    #pragma unroll
    for (int u = 0; u < 3; ++u){
      float rr[28];
      #pragma unroll
      for (int j = 0; j < 28; ++j) rr[j] = xg[(h + u)*29 + j];
      #pragma unroll
      for (int v = 0; v < 3; ++v){
        float wv = wt[u*3 + v];
        #pragma unroll
        for (int w = 0; w < 26; ++w) acc[w] = fmaf(rr[w + v], wv, acc[w]);
      }
    }
    float s1 = 0.f, s2 = 0.f;
    #pragma unroll
    for (int w = 0; w < 26; ++w){ s1 += acc[w]; s2 += acc[w]*acc[w]; }
    atomicAdd(&lsum[o], s1); atomicAdd(&lss[o], s2);
  }
  __syncthreads();
  if (tid < 10){ atomicAdd(&ssum[tid], lsum[tid]); atomicAdd(&ssq[tid], lss[tid]); }
}

// ---------------- bn stats -> scale/shift ----------------
__global__ void k_finalize(const float* __restrict__ ssum, const float* __restrict__ ssq,
                           const void* __restrict__ g, const void* __restrict__ bb,
                           const int* __restrict__ ctrl,
                           float invN, float* __restrict__ scale, float* __restrict__ shift){
  int c = threadIdx.x;
  if (c < 10){
    float m = ssum[c] * invN;
    float v = fmaxf(ssq[c] * invN - m*m, 0.f);
    float sc = ldin(g, c, ctrl[0]) * rsqrtf(v + 2e-5f);
    scale[c] = sc;
    shift[c] = ldin(bb, c, ctrl[0]) - m * sc;
  }
}

// ---------------- L2 attention (separate: LDS too big to fuse into conv2m) ----------------
__global__ __launch_bounds__(128) void k_att2(const float* __restrict__ xa,
                                              const void* __restrict__ c1,
                                              const float* __restrict__ sc1,
                                              const float* __restrict__ sh1,
                                              const void* __restrict__ aw,
                                              const int* __restrict__ ctrl,
                                              float* __restrict__ attf){
  __shared__ float xs[28*29];
  __shared__ float wr1[360];
  __shared__ float ps[8*26*33];
  __shared__ float wl[1568];
  __shared__ float scs[10], shs[10];
  int b = blockIdx.x, tid = threadIdx.x;
  int f32 = ctrl[0];
  for (int i = tid; i < 784; i += 128){
    int row = i / 28, col = i % 28;
    xs[row*29 + col] = xa[(size_t)b*784 + i];
  }
  for (int i = tid; i < 360; i += 128){
    int r = i / 90, rem = i % 90, o = rem / 9, t = rem % 9;
    wr1[i] = ldin(c1, o*9 + rot_src<3>(r, t), f32);
  }
  for (int i = tid; i < 8*26*33; i += 128) ps[i] = 0.f;
  for (int i = tid; i < 1568; i += 128){
    int r = i / 392, rem = i % 392, i2 = rem / 196, s = (rem % 196)/49, t = rem % 49;
    int sp = (s - r) & 3;
    wl[i] = ldin(aw, (i2*4 + sp)*49 + rot_src<7>(r, t), f32);
  }
  if (tid < 10){ scs[tid] = sc1[tid]; shs[tid] = sh1[tid]; }
  __syncthreads();
  if (tid < 104){
    int s = tid / 26, h = tid % 26;
    float msum[26], mmax[26];
    #pragma unroll
    for (int w = 0; w < 26; ++w){ msum[w] = 0.f; mmax[w] = 0.f; }
    for (int o = 0; o < 10; ++o){
      const float* wb = wr1 + (s*10 + o)*9;
      float acc[26];
      #pragma unroll
      for (int w = 0; w < 26; ++w) acc[w] = 0.f;
      #pragma unroll
      for (int u = 0; u < 3; ++u){
        float rr[28];
        #pragma unroll
        for (int j = 0; j < 28; ++j) rr[j] = xs[(h + u)*29 + j];
        #pragma unroll
        for (int v = 0; v < 3; ++v){
          float wv = wb[u*3 + v];
          #pragma unroll
          for (int w = 0; w < 26; ++w) acc[w] = fmaf(rr[w + v], wv, acc[w]);
        }
      }
      float a_sc = scs[o], a_sh = shs[o];
      #pragma unroll
      for (int w = 0; w < 26; ++w){
        float val = fmaxf(fmaf(acc[w], a_sc, a_sh), 0.f);
        msum[w] += val; mmax[w] = fmaxf(mmax[w], val);
      }
    }
    #pragma unroll
    for (int w = 0; w < 26; ++w){
      ps[s*858 + h*33 + 3 + w] = msum[w] * 0.1f;
      ps[(4 + s)*858 + h*33 + 3 + w] = mmax[w];
    }
  }
  __syncthreads();
  if (tid < 104){
    int r = tid / 26, h = tid % 26;
    float acc[26];
    #pragma unroll
    for (int w = 0; w < 26; ++w) acc[w] = 0.f;
    for (int c = 0; c < 8; ++c){
      const float* wb = wl + r*392 + c*49;
      const float* pb = ps + c*858;
      #pragma unroll
      for (int u = 0; u < 7; ++u){
        int row = h + u - 3;
        if (row < 0 || row >= 26) continue;
        float rr[32];
        #pragma unroll
        for (int j = 0; j < 32; ++j) rr[j] = pb[row*33 + j];
        #pragma unroll
        for (int v = 0; v < 7; ++v){
          float wv = wb[u*7 + v];
          #pragma unroll
          for (int w = 0; w < 26; ++w) acc[w] = fmaf(rr[w + v], wv, acc[w]);
        }
      }
    }
    size_t base = ((size_t)b*4 + r)*676 + (size_t)h*26;
    #pragma unroll
    for (int w = 0; w < 26; ++w) attf[base + w] = sigm(acc[w]);
  }
}

// ---------------- L2 conv via MFMA: row-strip staging (ch-fastest), K=40-packed, global B-frags ----------------
__global__ __launch_bounds__(512, 4) void k_conv2m(const float* __restrict__ xa,
                                                const void* __restrict__ c1,
                                                const float* __restrict__ sc1,
                                                const float* __restrict__ sh1,
                                                const float* __restrict__ attm,
                                                const short* __restrict__ btg,
                                                const int* __restrict__ ctrl,
                                                bf* __restrict__ ap2,
                                                float* __restrict__ ssum, float* __restrict__ ssq){
  __shared__ alignas(16) float xs2[784];
  __shared__ float wr1[360];
  __shared__ alignas(16) float attL[4*676];
  __shared__ alignas(16) short xin[676*40];
  __shared__ float lsum[16], lss[16];
  int tid = threadIdx.x, b = blockIdx.x;
  int f32 = ctrl[0];
  for (int i = tid; i < 784; i += 512) xs2[i] = xa[(size_t)b*784 + i];
  for (int i = tid; i < 360; i += 512){
    int r = i / 90, rem = i % 90, o = rem / 9, t = rem % 9;
    wr1[i] = ldin(c1, o*9 + rot_src<3>(r, t), f32);
  }
  for (int i = tid; i < 2704; i += 512) attL[i] = attm[(size_t)b*2704 + i];
  if (tid < 16){ lsum[tid] = 0.f; lss[tid] = 0.f; }
  __syncthreads();
  for (int it = tid; it < 1040; it += 512){
    int row = it / 40, ch = it % 40;
    int ci = ch >> 2, s = ch & 3;
    float wt[9];
    {
      const float* wb = wr1 + (s*10 + ci)*9;
      #pragma unroll
      for (int t = 0; t < 9; ++t) wt[t] = wb[t];
    }
    float sc = sc1[ci], sh = sh1[ci];
    float acc[26];
    #pragma unroll
    for (int w = 0; w < 26; ++w) acc[w] = 0.f;
    #pragma unroll
    for (int u = 0; u < 3; ++u){
      float rr[28];
      const float4* rp = (const float4*)(xs2 + (row + u)*28);
      #pragma unroll
      for (int j = 0; j < 7; ++j){ float4 q = rp[j]; rr[4*j]=q.x; rr[4*j+1]=q.y; rr[4*j+2]=q.z; rr[4*j+3]=q.w; }
      #pragma unroll
      for (int v = 0; v < 3; ++v){
        float wv = wt[u*3 + v];
        #pragma unroll
        for (int w = 0; w < 26; ++w) acc[w] = fmaf(rr[w + v], wv, acc[w]);
      }
    }
    const float* ap = attL + s*676 + row*26;
    #pragma unroll
    for (int w = 0; w < 26; ++w){
      float v = fmaxf(fmaf(acc[w], sc, sh), 0.f) * ap[w];
      xin[(row*26 + w)*40 + ch] = bfbits(v);
    }
  }
  __syncthreads();

  int wv = tid >> 6, lane = tid & 63, lm = lane & 15, lq = lane >> 4;
  short8x z8 = {0,0,0,0,0,0,0,0};
  short8x b32[9], bt1[9];
  int curNt = -1, n = 0, o = 0;
  for (int u = wv; u < 54; u += 8){
    int nt = u / 18, mp = u % 18;
    if (nt != curNt){
      curNt = nt; n = nt*16 + lm; o = n >> 2;
      #pragma unroll
      for (int t = 0; t < 9; ++t){
        b32[t] = *(const short8x*)(btg + (((t*4 + lq)*48 + n) << 3));
        bt1[t] = z8;
        if (lq == 0) bt1[t] = *(const short8x*)(btg + 13824 + ((t*48 + n) << 3));
      }
    }
    int mt0 = mp*2, mt1 = mp*2 + 1;
    int mA0 = mt0*16 + lm, mA1 = mt1*16 + lm;
    int qi0 = mA0 >> 2, sub0 = mA0 & 3;
    int h00 = 2*(qi0/12) + (sub0 >> 1), w00 = 2*(qi0%12) + (sub0 & 1);
    int qi1 = mA1 >> 2, sub1 = mA1 & 3;
    int h01 = 2*(qi1/12) + (sub1 >> 1), w01 = 2*(qi1%12) + (sub1 & 1);
    f32x4 acc0 = {0.f,0.f,0.f,0.f}, acc1 = {0.f,0.f,0.f,0.f};
    #pragma unroll
    for (int t = 0; t < 9; ++t){
      int sp0 = (h00 + t/3)*26 + (w00 + t%3);
      int sp1 = (h01 + t/3)*26 + (w01 + t%3);
      short8x a00 = *(const short8x*)&xin[sp0*40 + lq*8];
      short8x a01 = *(const short8x*)&xin[sp1*40 + lq*8];
      short8x a10 = z8, a11 = z8;
      if (lq == 0){
        a10 = *(const short8x*)&xin[sp0*40 + 32];
        a11 = *(const short8x*)&xin[sp1*40 + 32];
      }
      acc0 = __builtin_amdgcn_mfma_f32_16x16x32_bf16(a00, b32[t], acc0, 0, 0, 0);
      acc1 = __builtin_amdgcn_mfma_f32_16x16x32_bf16(a01, b32[t], acc1, 0, 0, 0);
      acc0 = __builtin_amdgcn_mfma_f32_16x16x32_bf16(a10, bt1[t], acc0, 0, 0, 0);
      acc1 = __builtin_amdgcn_mfma_f32_16x16x32_bf16(a11, bt1[t], acc1, 0, 0, 0);
    }
    if (n < 40){
      float s1 = acc0[0]+acc0[1]+acc0[2]+acc0[3] + acc1[0]+acc1[1]+acc1[2]+acc1[3];
      float s2 = acc0[0]*acc0[0]+acc0[1]*acc0[1]+acc0[2]*acc0[2]+acc0[3]*acc0[3]
               + acc1[0]*acc1[0]+acc1[1]*acc1[1]+acc1[2]*acc1[2]+acc1[3]*acc1[3];
      atomicAdd(&lsum[o], s1); atomicAdd(&lss[o], s2);
      float mx0 = fmaxf(fmaxf(acc0[0], acc0[1]), fmaxf(acc0[2], acc0[3]));
      float mx1 = fmaxf(fmaxf(acc1[0], acc1[1]), fmaxf(acc1[2], acc1[3]));
      size_t pbase = ((size_t)b*40 + n)*144;
      stv(ap2 + pbase + mt0*4 + lq, mx0);
      stv(ap2 + pbase + mt1*4 + lq, mx1);
    }
  }
  __syncthreads();
  if (tid < 10){ atomicAdd(&ssum[tid], lsum[tid]); atomicAdd(&ssq[tid], lss[tid]); }
}

// ---------------- fused att + GG conv via MFMA (L3/L4): one image/block ----------------
template<int HIN, int NT, typename TI>
__global__ __launch_bounds__(NT) void k_fusedm(const TI* __restrict__ act,
                                               const float* __restrict__ scale,
                                               const float* __restrict__ shift,
                                               const void* __restrict__ aw,
                                               const short* __restrict__ btg,
                                               const int* __restrict__ ctrl,
                                               float* __restrict__ out,
                                               float* __restrict__ ssum, float* __restrict__ ssq){
  constexpr int HOUT = HIN - 2, WOUT = HIN - 2;
  constexpr int M = HOUT*WOUT, HW = HIN*HIN;
  constexpr int WG = (HIN + 6) | 1;
  constexpr int MT = (M + 15)/16, MU = (MT + 1)/2, UNITS = MU*3;
  constexpr int NWV = NT/64;
  __shared__ float xf[HW*41];                 // bnrelu f32, row stride 41 (odd)
  __shared__ float ps[8*HIN*WG];
  __shared__ float wl[1568];
  __shared__ float attL[4*HW];
  __shared__ alignas(16) short xin[HW*40];
  __shared__ float lsum[16], lss[16];
  int tid = threadIdx.x, b = blockIdx.x;
  int f32 = ctrl[0];
  if (tid < 16){ lsum[tid] = 0.f; lss[tid] = 0.f; }
  for (int i = tid; i < 8*HIN*WG; i += NT) ps[i] = 0.f;
  for (int i = tid; i < 1568; i += NT){
    int r = i / 392, rem = i % 392, i2 = rem / 196, s = (rem % 196)/49, t = rem % 49;
    int sp = (s - r) & 3;
    wl[i] = ldin(aw, (i2*4 + sp)*49 + rot_src<7>(r, t), f32);
  }
  // stage xf: items (ch, sp) sp-fastest -> coalesced global reads, conflict-free LDS writes
  for (int i = tid; i < 40*HW; i += NT){
    int ch = i / HW, sp = i % HW;
    int ci = ch >> 2;
    float a = ldv(act + ((size_t)b*40 + ch)*HW + sp);
    xf[sp*41 + ch] = fmaxf(fmaf(a, scale[ci], shift[ci]), 0.f);
  }
  __syncthreads();
  // pooled planes: items (s, sp), sp fastest
  for (int i = tid; i < 4*HW; i += NT){
    int s = i / HW, sp = i % HW;
    float sum = 0.f, mx = 0.f;
    #pragma unroll
    for (int ci = 0; ci < 10; ++ci){
      float v = xf[sp*41 + ci*4 + s];
      sum += v; mx = fmaxf(mx, v);
    }
    int row = sp / HIN, col = sp % HIN;
    ps[s*HIN*WG + row*WG + 3 + col] = sum * 0.1f;
    ps[(4 + s)*HIN*WG + row*WG + 3 + col] = mx;
  }
  __syncthreads();
  // att conv: items (r, h)
  for (int it = tid; it < 4*HIN; it += NT){
    int r = it / HIN, h = it % HIN;
    float acc[HIN];
    #pragma unroll
    for (int w = 0; w < HIN; ++w) acc[w] = 0.f;
    for (int c = 0; c < 8; ++c){
      const float* wb = wl + r*392 + c*49;
      const float* pb = ps + c*HIN*WG;
      #pragma unroll
      for (int u = 0; u < 7; ++u){
        int row = h + u - 3;
        if (row < 0 || row >= HIN) continue;
        float rr[HIN + 6];
        #pragma unroll
        for (int j = 0; j < HIN + 6; ++j) rr[j] = pb[row*WG + j];
        #pragma unroll
        for (int v = 0; v < 7; ++v){
          float wv = wb[u*7 + v];
          #pragma unroll
          for (int w = 0; w < HIN; ++w) acc[w] = fmaf(rr[w + v], wv, acc[w]);
        }
      }
    }
    #pragma unroll
    for (int w = 0; w < HIN; ++w) attL[r*HW + h*HIN + w] = sigm(acc[w]);
  }
  __syncthreads();
  // gate: items (sp, ch) ch-fastest
  for (int i = tid; i < HW*40; i += NT){
    int sp = i / 40, ch = i % 40;
    xin[i] = bfbits(xf[sp*41 + ch] * attL[(ch & 3)*HW + sp]);
  }
  __syncthreads();
  // MFMA conv phase
  int wv = tid >> 6, lane = tid & 63, lm = lane & 15, lq = lane >> 4;
  short8x z8 = {0,0,0,0,0,0,0,0};
  short8x b32[9], bt1[9];
  int curNt = -1, n = 0, o = 0;
  for (int u = wv; u < UNITS; u += NWV){
    int nt = u / MU, mu = u % MU;
    if (nt != curNt){
      curNt = nt; n = nt*16 + lm; o = n >> 2;
      #pragma unroll
      for (int t = 0; t < 9; ++t){
        b32[t] = *(const short8x*)(btg + (((t*4 + lq)*48 + n) << 3));
        bt1[t] = z8;
        if (lq == 0) bt1[t] = *(const short8x*)(btg + 13824 + ((t*48 + n) << 3));
      }
    }
    int mt0 = mu*2, mt1 = mu*2 + 1;
    int mA0 = mt0*16 + lm; if (mA0 > M-1) mA0 = M-1;
    int mA1 = mt1*16 + lm; if (mA1 > M-1) mA1 = M-1;
    int mh0 = mA0 / WOUT, mw0 = mA0 % WOUT;
    int mh1 = mA1 / WOUT, mw1 = mA1 % WOUT;
    f32x4 acc0 = {0.f,0.f,0.f,0.f}, acc1 = {0.f,0.f,0.f,0.f};
    #pragma unroll
    for (int t = 0; t < 9; ++t){
      int sp0 = (mh0 + t/3)*HIN + (mw0 + t%3);
      int sp1 = (mh1 + t/3)*HIN + (mw1 + t%3);
      short8x a00 = *(const short8x*)&xin[sp0*40 + lq*8];
      short8x a01 = *(const short8x*)&xin[sp1*40 + lq*8];
      short8x a10 = z8, a11 = z8;
      if (lq == 0){
        a10 = *(const short8x*)&xin[sp0*40 + 32];
        a11 = *(const short8x*)&xin[sp1*40 + 32];
      }
      acc0 = __builtin_amdgcn_mfma_f32_16x16x32_bf16(a00, b32[t], acc0, 0, 0, 0);
      acc1 = __builtin_amdgcn_mfma_f32_16x16x32_bf16(a01, b32[t], acc1, 0, 0, 0);
      acc0 = __builtin_amdgcn_mfma_f32_16x16x32_bf16(a10, bt1[t], acc0, 0, 0, 0);
      acc1 = __builtin_amdgcn_mfma_f32_16x16x32_bf16(a11, bt1[t], acc1, 0, 0, 0);
    }
    if (n < 40){
      float s1 = 0.f, s2 = 0.f;
      size_t obase = ((size_t)b*40 + n)*M;
      #pragma unroll
      for (int reg = 0; reg < 4; ++reg){
        int m0 = mt0*16 + lq*4 + reg;
        if (m0 < M){ float v = acc0[reg]; s1 += v; s2 += v*v; out[obase + m0] = v; }
        int m1 = mt1*16 + lq*4 + reg;
        if (m1 < M){ float v = acc1[reg]; s1 += v; s2 += v*v; out[obase + m1] = v; }
      }
      atomicAdd(&lsum[o], s1); atomicAdd(&lss[o], s2);
    }
  }
  __syncthreads();
  if (tid < 10){ atomicAdd(&ssum[tid], lsum[tid]); atomicAdd(&ssq[tid], lss[tid]); }
}

// ---------------- fused att + f32 GG conv (L5/L6): bit-identical conv math to k_conv_gg ----------------
template<int HIN, int SR, int NT>
__global__ __launch_bounds__(NT) void k_fusedf(const float* __restrict__ act,
                                               const float* __restrict__ scale,
                                               const float* __restrict__ shift,
                                               const void* __restrict__ aw,
                                               const void* __restrict__ cw,
                                               const int* __restrict__ ctrl,
                                               float* __restrict__ out,
                                               float* __restrict__ ssum, float* __restrict__ ssq){
  constexpr int K = 3;
  constexpr int WIN = HIN;
  constexpr int HOUT = HIN - 2, WOUT = HIN - 2;
  constexpr int NS = HOUT / SR;
  constexpr int WP = WIN | 1;
  constexpr int XP = HIN*WP + 1;              // plane stride (breaks power-of-2 across planes)
  constexpr int HW = HIN*WIN;
  constexpr int WG = (WIN + 6) | 1;
  __shared__ float xf[40*XP];
  __shared__ float wl[3600];
  __shared__ float wla[1568];
  __shared__ float ps[8*HIN*WG];
  __shared__ float attL[4*HW];
  __shared__ float lsum[16], lss[16];
  int tid = threadIdx.x, b = blockIdx.x;
  int f32 = ctrl[0];
  if (tid < 16){ lsum[tid] = 0.f; lss[tid] = 0.f; }
  for (int i = tid; i < 8*HIN*WG; i += NT) ps[i] = 0.f;
  for (int i = tid; i < 3600; i += NT) wl[i] = ldin(cw, i, f32);
  for (int i = tid; i < 1568; i += NT){
    int r = i / 392, rem = i % 392, i2 = rem / 196, s = (rem % 196)/49, t = rem % 49;
    int sp = (s - r) & 3;
    wla[i] = ldin(aw, (i2*4 + sp)*49 + rot_src<7>(r, t), f32);
  }
  // stage xf = relu(bn(act)), ungated; guard cols zero
  for (int i = tid; i < 40*HIN*WP; i += NT){
    int c = i / (HIN*WP), rem = i % (HIN*WP), rr = rem / WP, col = rem % WP;
    float v = 0.f;
    if (col < WIN){
      int ch = c >> 2;
      float a = ldv(act + ((size_t)b*40 + c)*HW + (size_t)rr*WIN + col);
      v = fmaxf(fmaf(a, scale[ch], shift[ch]), 0.f);
    }
    xf[c*XP + rr*WP + col] = v;
  }
  __syncthreads();
  // pooled planes: items (s, sp)
  for (int i = tid; i < 4*HW; i += NT){
    int s = i / HW, sp = i % HW;
    int row = sp / WIN, col = sp % WIN;
    float sum = 0.f, mx = 0.f;
    #pragma unroll
    for (int ci = 0; ci < 10; ++ci){
      float v = xf[(ci*4 + s)*XP + row*WP + col];
      sum += v; mx = fmaxf(mx, v);
    }
    ps[s*HIN*WG + row*WG + 3 + col] = sum * 0.1f;
    ps[(4 + s)*HIN*WG + row*WG + 3 + col] = mx;
  }
  __syncthreads();
  // att conv: items (r, h)
  for (int it = tid; it < 4*HIN; it += NT){
    int r = it / HIN, h = it % HIN;
    float acc[WIN];
    #pragma unroll
    for (int w = 0; w < WIN; ++w) acc[w] = 0.f;
    for (int c = 0; c < 8; ++c){
      const float* wb = wla + r*392 + c*49;
      const float* pb = ps + c*HIN*WG;
      #pragma unroll
      for (int u = 0; u < 7; ++u){
        int row = h + u - 3;
        if (row < 0 || row >= HIN) continue;
        float rr[WIN + 6];
        #pragma unroll
        for (int j = 0; j < WIN + 6; ++j) rr[j] = pb[row*WG + j];
        #pragma unroll
        for (int v = 0; v < 7; ++v){
          float wv = wb[u*7 + v];
          #pragma unroll
          for (int w = 0; w < WIN; ++w) acc[w] = fmaf(rr[w + v], wv, acc[w]);
        }
      }
    }
    #pragma unroll
    for (int w = 0; w < WIN; ++w) attL[r*HW + h*WIN + w] = sigm(acc[w]);
  }
  __syncthreads();
  // gate xf in place
  for (int i = tid; i < 40*HW; i += NT){
    int c = i / HW, sp = i % HW;
    int row = sp / WIN, col = sp % WIN;
    xf[c*XP + row*WP + col] *= attL[(c & 3)*HW + sp];
  }
  __syncthreads();
  // conv phase (identical math/order to k_conv_gg)
  for (int it = tid; it < 40*NS; it += NT){
    int o = it / (4*NS), rem = it % (4*NS), r = rem / NS, hs = rem % NS;
    int h0 = hs * SR;
    int perm[9];
    #pragma unroll
    for (int t = 0; t < 9; ++t) perm[t] = rot_src<3>(r, t);
    float acc[SR][WOUT];
    #pragma unroll
    for (int a = 0; a < SR; ++a)
      #pragma unroll
      for (int w = 0; w < WOUT; ++w) acc[a][w] = 0.f;
    for (int ci = 0; ci < 10; ++ci){
      #pragma unroll
      for (int s = 0; s < 4; ++s){
        int sp = (s - r) & 3;
        const float* wb = wl + (size_t)((o*10 + ci)*4 + sp)*9;
        float wt[9];
        #pragma unroll
        for (int t = 0; t < 9; ++t) wt[t] = wb[perm[t]];
        const float* ib = xf + (ci*4 + s)*XP;
        #pragma unroll
        for (int ri = 0; ri < SR + K - 1; ++ri){
          float rr[WP];
          #pragma unroll
          for (int j = 0; j < WP; ++j) rr[j] = ib[(h0 + ri)*WP + j];
          #pragma unroll
          for (int u = 0; u < K; ++u){
            int orr = ri - u;
            if (orr < 0 || orr >= SR) continue;
            #pragma unroll
            for (int v = 0; v < K; ++v){
              float wv = wt[u*K + v];
              #pragma unroll
              for (int w = 0; w < WOUT; ++w) acc[orr][w] = fmaf(rr[w + v], wv, acc[orr][w]);
            }
          }
        }
      }
    }
    float s1 = 0.f, s2 = 0.f;
    #pragma unroll
    for (int a = 0; a < SR; ++a)
      #pragma unroll
      for (int w = 0; w < WOUT; ++w){ s1 += acc[a][w]; s2 += acc[a][w]*acc[a][w]; }
    atomicAdd(&lsum[o], s1); atomicAdd(&lss[o], s2);
    #pragma unroll
    for (int a = 0; a < SR; ++a){
      size_t base = ((size_t)b*40 + o*4 + r)*HOUT*WOUT + (size_t)(h0 + a)*WOUT;
      #pragma unroll
      for (int w = 0; w < WOUT; ++w) out[base + w] = acc[a][w];
    }
  }
  __syncthreads();
  if (tid < 10){ atomicAdd(&ssum[tid], lsum[tid]); atomicAdd(&ssq[tid], lss[tid]); }
}

// ---------------- generic GG spatial attention (L7 only) ----------------
template<int H, int W, int NT, typename TA>
__global__ __launch_bounds__(NT) void k_att_gg(const TA* __restrict__ act,
                                               const float* __restrict__ scale,
                                               const float* __restrict__ shift,
                                               const void* __restrict__ aw,
                                               const int* __restrict__ ctrl,
                                               float* __restrict__ att){
  constexpr int WG = (W + 6) | 1;
  constexpr int HW = H*W;
  __shared__ float ps[8*H*WG];
  __shared__ float wl[1568];
  int b = blockIdx.x, tid = threadIdx.x;
  int f32 = ctrl[0];
  for (int i = tid; i < 4*H*WG; i += NT){
    int s = i / (H*WG), rem = i % (H*WG), row = rem / WG, col = rem % WG;
    int cc = col - 3;
    float mn = 0.f, mx = 0.f;
    if (cc >= 0 && cc < W){
      float sum = 0.f; mx = 0.f;
      const TA* ap = act + (size_t)b*40*HW + (size_t)s*HW + row*W + cc;
      #pragma unroll
      for (int c = 0; c < 10; ++c){
        float v = fmaxf(fmaf(ldv(ap + (size_t)c*4*HW), scale[c], shift[c]), 0.f);
        sum += v; mx = fmaxf(mx, v);
      }
      mn = sum * 0.1f;
    }
    ps[s*H*WG + row*WG + col] = mn;
    ps[(4 + s)*H*WG + row*WG + col] = mx;
  }
  for (int i = tid; i < 1568; i += NT){
    int r = i / 392, rem = i % 392, i2 = rem / 196, s = (rem % 196)/49, t = rem % 49;
    int sp = (s - r) & 3;
    wl[i] = ldin(aw, (i2*4 + sp)*49 + rot_src<7>(r, t), f32);
  }
  __syncthreads();
  for (int it = tid; it < 4*H; it += NT){
    int r = it / H, h = it % H;
    float acc[W];
    #pragma unroll
    for (int w = 0; w < W; ++w) acc[w] = 0.f;
    for (int c = 0; c < 8; ++c){
      const float* wb = wl + r*392 + c*49;
      const float* pb = ps + c*H*WG;
      #pragma unroll
      for (int u = 0; u < 7; ++u){
        int row = h + u - 3;
        if (row < 0 || row >= H) continue;
        float rr[W + 6];
        #pragma unroll
        for (int j = 0; j < W + 6; ++j) rr[j] = pb[row*WG + j];
        #pragma unroll
        for (int v = 0; v < 7; ++v){
          float wv = wb[u*7 + v];
          #pragma unroll
          for (int w = 0; w < W; ++w) acc[w] = fmaf(rr[w + v], wv, acc[w]);
        }
      }
    }
    size_t base = ((size_t)b*4 + r)*HW + (size_t)h*W;
    #pragma unroll
    for (int w = 0; w < W; ++w) att[base + w] = sigm(acc[w]);
  }
}

// ---------------- fp32 GG conv (L7 only) ----------------
template<int HIN, int WIN, int K, int SR, int NT, bool STATS, typename TI, typename TO>
__global__ __launch_bounds__(NT) void k_conv_gg(const TI* __restrict__ act,
                                                const float* __restrict__ scale,
                                                const float* __restrict__ shift,
                                                const float* __restrict__ attm,
                                                const void* __restrict__ cw,
                                                const int* __restrict__ ctrl,
                                                TO* __restrict__ out,
                                                float* __restrict__ ssum, float* __restrict__ ssq){
  constexpr int HOUT = HIN - K + 1;
  constexpr int WOUT = WIN - K + 1;
  constexpr int NS   = HOUT / SR;
  constexpr int WP   = WIN | 1;
  constexpr int NW   = 10*10*4*K*K;
  __shared__ float xin[40*HIN*WP];
  __shared__ float wl[NW];
  __shared__ float lsum[16], lss[16];
  int tid = threadIdx.x;
  int b = blockIdx.x;
  int f32 = ctrl[0];
  for (int i = tid; i < 40*HIN*WP; i += NT){
    int c = i / (HIN*WP), rem = i % (HIN*WP), rr = rem / WP, col = rem % WP;
    float v = 0.f;
    if (col < WIN){
      int ch = c >> 2, s = c & 3;
      float a = ldv(act + ((size_t)b*40 + c)*HIN*WIN + (size_t)rr*WIN + col);
      a = fmaxf(fmaf(a, scale[ch], shift[ch]), 0.f);
      v = a * attm[((size_t)b*4 + s)*HIN*WIN + (size_t)rr*WIN + col];
    }
    xin[i] = v;
  }
  for (int i = tid; i < NW; i += NT) wl[i] = ldin(cw, i, f32);
  if (STATS && tid < 16){ lsum[tid] = 0.f; lss[tid] = 0.f; }
  __syncthreads();
  for (int it = tid; it < 40*NS; it += NT){
    int o = it / (4*NS), rem = it % (4*NS), r = rem / NS, hs = rem % NS;
    int h0 = hs * SR;
    int perm[K*K];
    #pragma unroll
    for (int t = 0; t < K*K; ++t) perm[t] = rot_src<K>(r, t);
    float acc[SR][WOUT];
    #pragma unroll
    for (int a = 0; a < SR; ++a)
      #pragma unroll
      for (int w = 0; w < WOUT; ++w) acc[a][w] = 0.f;
    for (int ci = 0; ci < 10; ++ci){
      #pragma unroll
      for (int s = 0; s < 4; ++s){
        int sp = (s - r) & 3;
        const float* wb = wl + (size_t)((o*10 + ci)*4 + sp)*K*K;
        float wt[K*K];
        #pragma unroll
        for (int t = 0; t < K*K; ++t) wt[t] = wb[perm[t]];
        const float* ib = xin + (ci*4 + s)*HIN*WP;
        #pragma unroll
        for (int ri = 0; ri < SR + K - 1; ++ri){
          float rr[WP];
          #pragma unroll
          for (int j = 0; j < WP; ++j) rr[j] = ib[(h0 + ri)*WP + j];
          #pragma unroll
          for (int u = 0; u < K; ++u){
            int orr = ri - u;
            if (orr < 0 || orr >= SR) continue;
            #pragma unroll
            for (int v = 0; v < K; ++v){
              float wv = wt[u*K + v];
              #pragma unroll
              for (int w = 0; w < WOUT; ++w) acc[orr][w] = fmaf(rr[w + v], wv, acc[orr][w]);
            }
          }
        }
      }
    }
    if (STATS){
      float s1 = 0.f, s2 = 0.f;
      #pragma unroll
      for (int a = 0; a < SR; ++a)
        #pragma unroll
        for (int w = 0; w < WOUT; ++w){ s1 += acc[a][w]; s2 += acc[a][w]*acc[a][w]; }
      atomicAdd(&lsum[o], s1); atomicAdd(&lss[o], s2);
    }
    #pragma unroll
    for (int a = 0; a < SR; ++a){
      size_t base = ((size_t)b*40 + o*4 + r)*HOUT*WOUT + (size_t)(h0 + a)*WOUT;
      #pragma unroll
      for (int w = 0; w < WOUT; ++w) stv(out + base + w, acc[a][w]);
    }
  }
  if (STATS){
    __syncthreads();
    if (tid < 10){ atomicAdd(&ssum[tid], lsum[tid]); atomicAdd(&ssq[tid], lss[tid]); }
  }
}

// ---------------- group max over orientations, dual-dtype out ----------------
__global__ __launch_bounds__(256) void k_out_max(const float* __restrict__ y7, void* __restrict__ outp,
                                                 const int* __restrict__ ctrl){
  int idx = blockIdx.x * 256 + threadIdx.x;
  if (idx >= 20480) return;
  int f32 = ctrl[0];
  const float* p = y7 + (size_t)idx*4;
  float m = fmaxf(fmaxf(p[0], p[1]), fmaxf(p[2], p[3]));
  if (f32) ((float*)outp)[idx] = m;
  else stv((bf*)outp + idx, m);
}

extern "C" void kernel_launch(void* const* d_in, const int* in_sizes, int n_in,
                              void* d_out, int out_size, void* d_ws, size_t ws_size,
                              hipStream_t stream){
  (void)in_sizes; (void)n_in; (void)out_size; (void)ws_size;
  const void* x  = d_in[0];
  const void* c1 = d_in[1];
  const void* a1 = d_in[2];
  const void* c2 = d_in[3];
  const void* a2 = d_in[4];
  const void* c3 = d_in[5];
  const void* a3 = d_in[6];
  const void* c4 = d_in[7];
  const void* a4 = d_in[8];
  const void* c5 = d_in[9];
  const void* a5 = d_in[10];
  const void* c6 = d_in[11];
  const void* a6 = d_in[12];
  const void* c7 = d_in[13];
  const void* a7 = d_in[14];
  const void* bng[6] = {d_in[15],d_in[17],d_in[19],d_in[21],d_in[23],d_in[25]};
  const void* bnb[6] = {d_in[16],d_in[18],d_in[20],d_in[22],d_in[24],d_in[26]};

  // ---- arena ----
  size_t off = 0;
  char* wsb = (char*)d_ws;
  auto alloc = [&](size_t bytes)->void*{ void* p = wsb + off; off += (bytes + 255) & ~(size_t)255; return p; };
  int*   ctrl   = (int*)alloc(256);
  float* stats  = (float*)alloc(192*sizeof(float));
  float* scales = (float*)alloc(192*sizeof(float));
  short* btfr   = (short*)alloc(3*17280*2);
  char*  region1 = (char*)alloc(28573696);
  bf*    ap2 = (bf*)alloc((size_t)2048*40*144*2);
  float* yD  = (float*)alloc((size_t)2048*40*100*4);
  float* xa    = (float*)region1;
  float* attf2 = (float*)(region1 + 6422528);
  float* yE    = (float*)region1;
  float* attf3 = (float*)(region1 + 20971520);

  hipMemsetAsync(ctrl, 0, 1024, stream);
  k_detect<<<1, 64, 0, stream>>>(x, ctrl);
  k_build_bt<<<3, 256, 0, stream>>>(c2, c3, c4, ctrl, btfr);

  // L1
  k_l1<<<2048, 256, 0, stream>>>(x, a1, c1, ctrl, xa, stats + 0, stats + 16);
  k_finalize<<<1, 64, 0, stream>>>(stats + 0, stats + 16, bng[0], bnb[0], ctrl, 1.f/5537792.f, scales + 0, scales + 16);

  // L2
  k_att2<<<2048, 128, 0, stream>>>(xa, c1, scales + 0, scales + 16, a2, ctrl, attf2);
  k_conv2m<<<2048, 512, 0, stream>>>(xa, c1, scales + 0, scales + 16, attf2, btfr, ctrl, ap2, stats + 32, stats + 48);
  k_finalize<<<1, 64, 0, stream>>>(stats + 32, stats + 48, bng[1], bnb[1], ctrl, 1.f/4718592.f, scales + 32, scales + 48);

  // L3: fused att + MFMA conv, 12->10
  k_fusedm<12,256,bf><<<2048, 256, 0, stream>>>(ap2, scales + 32, scales + 48, a3, btfr + 17280, ctrl,
                                                yD, stats + 64, stats + 80);
  k_finalize<<<1, 64, 0, stream>>>(stats + 64, stats + 80, bng[2], bnb[2], ctrl, 1.f/819200.f, scales + 64, scales + 80);

  // L4: fused att + MFMA conv, 10->8
  k_fusedm<10,256,float><<<2048, 256, 0, stream>>>(yD, scales + 64, scales + 80, a4, btfr + 34560, ctrl,
                                                   yE, stats + 96, stats + 112);
  k_finalize<<<1, 64, 0, stream>>>(stats + 96, stats + 112, bng[3], bnb[3], ctrl, 1.f/524288.f, scales + 96, scales + 112);

  // L5: fused att + f32 conv, 8->6
  k_fusedf<8,2,192><<<2048, 192, 0, stream>>>(yE, scales + 96, scales + 112, a5, c5, ctrl,
                                              yD, stats + 128, stats + 144);
  k_finalize<<<1, 64, 0, stream>>>(stats + 128, stats + 144, bng[4], bnb[4], ctrl, 1.f/294912.f, scales + 128, scales + 144);

  // L6: fused att + f32 conv, 6->4
  k_fusedf<6,2,128><<<2048, 128, 0, stream>>>(yD, scales + 128, scales + 144, a6, c6, ctrl,
                                              yE, stats + 160, stats + 176);
  k_finalize<<<1, 64, 0, stream>>>(stats + 160, stats + 176, bng[5], bnb[5], ctrl, 1.f/131072.f, scales + 160, scales + 176);

  // L7: 4x4 -> 1x1, no bn; then orientation max
  k_att_gg<4,4,64,float><<<2048, 64, 0, stream>>>(yE, scales + 160, scales + 176, a7, ctrl, attf3);
  k_conv_gg<4,4,4,1,64,false,float,float><<<2048, 64, 0, stream>>>(yE, scales + 160, scales + 176,
                                                                attf3, c7, ctrl, yD, (float*)nullptr, (float*)nullptr);
  k_out_max<<<80, 256, 0, stream>>>(yD, d_out, ctrl);
}

// Round 10
// 953.994 us; speedup vs baseline: 1.0599x; 1.0599x over previous
//
#include <hip/hip_runtime.h>
#include <hip/hip_bf16.h>
#include <cstddef>

typedef __hip_bfloat16 bf;
typedef __attribute__((ext_vector_type(8))) short short8x;
typedef __attribute__((ext_vector_type(4))) float f32x4;

__device__ __forceinline__ float ldv(const float* p){ return *p; }
__device__ __forceinline__ float ldv(const bf* p){ return __bfloat162float(*p); }
__device__ __forceinline__ void stv(float* p, float v){ *p = v; }
__device__ __forceinline__ void stv(bf* p, float v){ *p = __float2bfloat16(v); }
__device__ __forceinline__ float sigm(float x){ return 1.f/(1.f + __expf(-x)); }
__device__ __forceinline__ short bfbits(float v){
  __hip_bfloat16 h = __float2bfloat16(v);
  return *(short*)&h;
}

__device__ __forceinline__ float ldin(const void* p, long i, int f32){
  return f32 ? ((const float*)p)[i] : __bfloat162float(((const bf*)p)[i]);
}

template<int K>
__device__ __forceinline__ int rot_src(int r, int t){
  int u = t / K, v = t % K;
  int s1 = v*K + (K-1-u);
  int s2 = (K-1-u)*K + (K-1-v);
  int s3 = (K-1-v)*K + u;
  return r==0 ? t : (r==1 ? s1 : (r==2 ? s2 : s3));
}

// ---------------- dtype detection ----------------
__global__ void k_detect(const void* x, int* ctrl){
  int lane = threadIdx.x;
  float mx = 0.f;
  for (int i = lane; i < 2048; i += 64){
    float v = __bfloat162float(((const bf*)x)[i]);
    if (v != v) v = 1e30f;
    mx = fmaxf(mx, fabsf(v));
  }
  #pragma unroll
  for (int off = 32; off > 0; off >>= 1) mx = fmaxf(mx, __shfl_xor(mx, off));
  if (lane == 0) ctrl[0] = (mx > 1e6f) ? 1 : 0;
}

// ---------------- build MFMA B-frag buffers (tail-merged layout), 18432 shorts/layer ----------------
// main: [0,13824)  = Bt32[t][kq][n48][8], k = kq*8+j  (k<32)
// tail: [13824,18432) = Btail[tg][lq][n48][8], tap = tg*4+lq, k = 32+j (zero if tap>8)
__global__ __launch_bounds__(256) void k_build_bt(const void* c2, const void* c3, const void* c4,
                                                  const int* __restrict__ ctrl, short* __restrict__ btg){
  const void* ws[3] = {c2, c3, c4};
  const void* cw = ws[blockIdx.x];
  short* outp = btg + blockIdx.x * 18432;
  int f32 = ctrl[0];
  for (int i = threadIdx.x; i < 18432; i += 256){
    int t, n, k;
    bool valid;
    if (i < 13824){
      t = i / 1536;
      int rem = i % 1536;
      int kq = rem / 384;
      n = (i >> 3) % 48;
      k = kq*8 + (i & 7);
      valid = (n < 40);
    } else {
      int j2 = i - 13824;
      int tg = j2 / 1536;
      int lq = (j2 % 1536) / 384;
      n = (j2 >> 3) % 48;
      k = 32 + (i & 7);
      t = tg*4 + lq;
      valid = (t < 9) && (n < 40);
    }
    float v = 0.f;
    if (valid){
      int o = n >> 2, r = n & 3, ci = k >> 2, s = k & 3;
      v = ldin(cw, ((o*10 + ci)*4 + ((s - r) & 3))*9 + rot_src<3>(r, t), f32);
    }
    outp[i] = bfbits(v);
  }
}

// ---------------- L1 fused: att1 gate + xa write + conv1 bn1-stats ----------------
__global__ __launch_bounds__(256) void k_l1(const void* __restrict__ x,
                                            const void* __restrict__ a1,
                                            const void* __restrict__ c1,
                                            const int* __restrict__ ctrl,
                                            float* __restrict__ xa,
                                            float* __restrict__ ssum, float* __restrict__ ssq){
  __shared__ float xs[784];
  __shared__ float ws[49];
  __shared__ float xg[28*29];
  __shared__ float wr1[360];
  __shared__ float lsum[16], lss[16];
  int b = blockIdx.x, tid = threadIdx.x;
  int f32 = ctrl[0];
  for (int i = tid; i < 784; i += 256) xs[i] = ldin(x, (long)b*784 + i, f32);
  if (tid < 49) ws[tid] = ldin(a1, tid, f32) + ldin(a1, 49 + tid, f32);
  for (int i = tid; i < 360; i += 256){
    int r = i / 90, rem = i % 90, o = rem / 9, t = rem % 9;
    wr1[i] = ldin(c1, o*9 + rot_src<3>(r, t), f32);
  }
  if (tid < 16){ lsum[tid] = 0.f; lss[tid] = 0.f; }
  __syncthreads();
  for (int p = tid; p < 784; p += 256){
    int h = p / 28, w = p % 28;
    float acc = 0.f;
    #pragma unroll
    for (int u = 0; u < 7; ++u){
      int hh = h + u - 3;
      if (hh < 0 || hh >= 28) continue;
      #pragma unroll
      for (int v = 0; v < 7; ++v){
        int ww = w + v - 3;
        if (ww < 0 || ww >= 28) continue;
        acc = fmaf(xs[hh*28 + ww], ws[u*7 + v], acc);
      }
    }
    float g = xs[p] * sigm(acc);
    xg[h*29 + w] = g;
    xa[(size_t)b*784 + p] = g;
  }
  __syncthreads();
  for (int it = tid; it < 1040; it += 256){
    int o = it / 104, rem = it % 104, r = rem / 26, h = rem % 26;
    float wt[9];
    #pragma unroll
    for (int t = 0; t < 9; ++t) wt[t] = wr1[(r*10 + o)*9 + t];
    float acc[26];
    #pragma unroll
    for (int w = 0; w < 26; ++w) acc[w] = 0.f;
    #pragma unroll
    for (int u = 0; u < 3; ++u){
      float rr[28];
      #pragma unroll
      for (int j = 0; j < 28; ++j) rr[j] = xg[(h + u)*29 + j];
      #pragma unroll
      for (int v = 0; v < 3; ++v){
        float wv = wt[u*3 + v];
        #pragma unroll
        for (int w = 0; w < 26; ++w) acc[w] = fmaf(rr[w + v], wv, acc[w]);
      }
    }
    float s1 = 0.f, s2 = 0.f;
    #pragma unroll
    for (int w = 0; w < 26; ++w){ s1 += acc[w]; s2 += acc[w]*acc[w]; }
    atomicAdd(&lsum[o], s1); atomicAdd(&lss[o], s2);
  }
  __syncthreads();
  if (tid < 10){ atomicAdd(&ssum[tid], lsum[tid]); atomicAdd(&ssq[tid], lss[tid]); }
}

// ---------------- bn stats -> scale/shift ----------------
__global__ void k_finalize(const float* __restrict__ ssum, const float* __restrict__ ssq,
                           const void* __restrict__ g, const void* __restrict__ bb,
                           const int* __restrict__ ctrl,
                           float invN, float* __restrict__ scale, float* __restrict__ shift){
  int c = threadIdx.x;
  if (c < 10){
    float m = ssum[c] * invN;
    float v = fmaxf(ssq[c] * invN - m*m, 0.f);
    float sc = ldin(g, c, ctrl[0]) * rsqrtf(v + 2e-5f);
    scale[c] = sc;
    shift[c] = ldin(bb, c, ctrl[0]) - m * sc;
  }
}

// ---------------- L2 attention ----------------
__global__ __launch_bounds__(128) void k_att2(const float* __restrict__ xa,
                                              const void* __restrict__ c1,
                                              const float* __restrict__ sc1,
                                              const float* __restrict__ sh1,
                                              const void* __restrict__ aw,
                                              const int* __restrict__ ctrl,
                                              float* __restrict__ attf){
  __shared__ float xs[28*29];
  __shared__ float wr1[360];
  __shared__ float ps[8*26*33];
  __shared__ float wl[1568];
  __shared__ float scs[10], shs[10];
  int b = blockIdx.x, tid = threadIdx.x;
  int f32 = ctrl[0];
  for (int i = tid; i < 784; i += 128){
    int row = i / 28, col = i % 28;
    xs[row*29 + col] = xa[(size_t)b*784 + i];
  }
  for (int i = tid; i < 360; i += 128){
    int r = i / 90, rem = i % 90, o = rem / 9, t = rem % 9;
    wr1[i] = ldin(c1, o*9 + rot_src<3>(r, t), f32);
  }
  for (int i = tid; i < 8*26*33; i += 128) ps[i] = 0.f;
  for (int i = tid; i < 1568; i += 128){
    int r = i / 392, rem = i % 392, i2 = rem / 196, s = (rem % 196)/49, t = rem % 49;
    int sp = (s - r) & 3;
    wl[i] = ldin(aw, (i2*4 + sp)*49 + rot_src<7>(r, t), f32);
  }
  if (tid < 10){ scs[tid] = sc1[tid]; shs[tid] = sh1[tid]; }
  __syncthreads();
  if (tid < 104){
    int s = tid / 26, h = tid % 26;
    float msum[26], mmax[26];
    #pragma unroll
    for (int w = 0; w < 26; ++w){ msum[w] = 0.f; mmax[w] = 0.f; }
    for (int o = 0; o < 10; ++o){
      const float* wb = wr1 + (s*10 + o)*9;
      float acc[26];
      #pragma unroll
      for (int w = 0; w < 26; ++w) acc[w] = 0.f;
      #pragma unroll
      for (int u = 0; u < 3; ++u){
        float rr[28];
        #pragma unroll
        for (int j = 0; j < 28; ++j) rr[j] = xs[(h + u)*29 + j];
        #pragma unroll
        for (int v = 0; v < 3; ++v){
          float wv = wb[u*3 + v];
          #pragma unroll
          for (int w = 0; w < 26; ++w) acc[w] = fmaf(rr[w + v], wv, acc[w]);
        }
      }
      float a_sc = scs[o], a_sh = shs[o];
      #pragma unroll
      for (int w = 0; w < 26; ++w){
        float val = fmaxf(fmaf(acc[w], a_sc, a_sh), 0.f);
        msum[w] += val; mmax[w] = fmaxf(mmax[w], val);
      }
    }
    #pragma unroll
    for (int w = 0; w < 26; ++w){
      ps[s*858 + h*33 + 3 + w] = msum[w] * 0.1f;
      ps[(4 + s)*858 + h*33 + 3 + w] = mmax[w];
    }
  }
  __syncthreads();
  if (tid < 104){
    int r = tid / 26, h = tid % 26;
    float acc[26];
    #pragma unroll
    for (int w = 0; w < 26; ++w) acc[w] = 0.f;
    for (int c = 0; c < 8; ++c){
      const float* wb = wl + r*392 + c*49;
      const float* pb = ps + c*858;
      #pragma unroll
      for (int u = 0; u < 7; ++u){
        int row = h + u - 3;
        if (row < 0 || row >= 26) continue;
        float rr[32];
        #pragma unroll
        for (int j = 0; j < 32; ++j) rr[j] = pb[row*33 + j];
        #pragma unroll
        for (int v = 0; v < 7; ++v){
          float wv = wb[u*7 + v];
          #pragma unroll
          for (int w = 0; w < 26; ++w) acc[w] = fmaf(rr[w + v], wv, acc[w]);
        }
      }
    }
    size_t base = ((size_t)b*4 + r)*676 + (size_t)h*26;
    #pragma unroll
    for (int w = 0; w < 26; ++w) attf[base + w] = sigm(acc[w]);
  }
}

// ---------------- L2 conv via MFMA: row-strip staging, tail-merged K (12 MFMA/tile) ----------------
__global__ __launch_bounds__(512, 4) void k_conv2m(const float* __restrict__ xa,
                                                const void* __restrict__ c1,
                                                const float* __restrict__ sc1,
                                                const float* __restrict__ sh1,
                                                const float* __restrict__ attm,
                                                const short* __restrict__ btg,
                                                const int* __restrict__ ctrl,
                                                bf* __restrict__ ap2,
                                                float* __restrict__ ssum, float* __restrict__ ssq){
  __shared__ alignas(16) float xs2[784];
  __shared__ float wr1[360];
  __shared__ alignas(16) float attL[4*676];
  __shared__ alignas(16) short xin[676*40];
  __shared__ float lsum[16], lss[16];
  int tid = threadIdx.x, b = blockIdx.x;
  int f32 = ctrl[0];
  for (int i = tid; i < 784; i += 512) xs2[i] = xa[(size_t)b*784 + i];
  for (int i = tid; i < 360; i += 512){
    int r = i / 90, rem = i % 90, o = rem / 9, t = rem % 9;
    wr1[i] = ldin(c1, o*9 + rot_src<3>(r, t), f32);
  }
  for (int i = tid; i < 2704; i += 512) attL[i] = attm[(size_t)b*2704 + i];
  if (tid < 16){ lsum[tid] = 0.f; lss[tid] = 0.f; }
  __syncthreads();
  for (int it = tid; it < 1040; it += 512){
    int row = it / 40, ch = it % 40;
    int ci = ch >> 2, s = ch & 3;
    float wt[9];
    {
      const float* wb = wr1 + (s*10 + ci)*9;
      #pragma unroll
      for (int t = 0; t < 9; ++t) wt[t] = wb[t];
    }
    float sc = sc1[ci], sh = sh1[ci];
    float acc[26];
    #pragma unroll
    for (int w = 0; w < 26; ++w) acc[w] = 0.f;
    #pragma unroll
    for (int u = 0; u < 3; ++u){
      float rr[28];
      const float4* rp = (const float4*)(xs2 + (row + u)*28);
      #pragma unroll
      for (int j = 0; j < 7; ++j){ float4 q = rp[j]; rr[4*j]=q.x; rr[4*j+1]=q.y; rr[4*j+2]=q.z; rr[4*j+3]=q.w; }
      #pragma unroll
      for (int v = 0; v < 3; ++v){
        float wv = wt[u*3 + v];
        #pragma unroll
        for (int w = 0; w < 26; ++w) acc[w] = fmaf(rr[w + v], wv, acc[w]);
      }
    }
    const float* ap = attL + s*676 + row*26;
    #pragma unroll
    for (int w = 0; w < 26; ++w){
      float v = fmaxf(fmaf(acc[w], sc, sh), 0.f) * ap[w];
      xin[(row*26 + w)*40 + ch] = bfbits(v);
    }
  }
  __syncthreads();

  int wv = tid >> 6, lane = tid & 63, lm = lane & 15, lq = lane >> 4;
  short8x bmain[9], btail[3];
  // per-lane tail tap offsets (clamped; B=0 pads tap>8)
  int tdh[3], tdw[3];
  #pragma unroll
  for (int tg = 0; tg < 3; ++tg){
    int tap = tg*4 + lq; if (tap > 8) tap = 8;
    tdh[tg] = tap / 3; tdw[tg] = tap % 3;
  }
  int curNt = -1, n = 0, o = 0;
  for (int u = wv; u < 54; u += 8){
    int nt = u / 18, mp = u % 18;
    if (nt != curNt){
      curNt = nt; n = nt*16 + lm; o = n >> 2;
      #pragma unroll
      for (int t = 0; t < 9; ++t)
        bmain[t] = *(const short8x*)(btg + (((t*4 + lq)*48 + n) << 3));
      #pragma unroll
      for (int tg = 0; tg < 3; ++tg)
        btail[tg] = *(const short8x*)(btg + 13824 + (((tg*4 + lq)*48 + n) << 3));
    }
    int mt0 = mp*2, mt1 = mp*2 + 1;
    int mA0 = mt0*16 + lm, mA1 = mt1*16 + lm;
    int qi0 = mA0 >> 2, sub0 = mA0 & 3;
    int h00 = 2*(qi0/12) + (sub0 >> 1), w00 = 2*(qi0%12) + (sub0 & 1);
    int qi1 = mA1 >> 2, sub1 = mA1 & 3;
    int h01 = 2*(qi1/12) + (sub1 >> 1), w01 = 2*(qi1%12) + (sub1 & 1);
    f32x4 acc0 = {0.f,0.f,0.f,0.f}, acc1 = {0.f,0.f,0.f,0.f};
    #pragma unroll
    for (int t = 0; t < 9; ++t){
      int sp0 = (h00 + t/3)*26 + (w00 + t%3);
      int sp1 = (h01 + t/3)*26 + (w01 + t%3);
      short8x a0 = *(const short8x*)&xin[sp0*40 + lq*8];
      short8x a1 = *(const short8x*)&xin[sp1*40 + lq*8];
      acc0 = __builtin_amdgcn_mfma_f32_16x16x32_bf16(a0, bmain[t], acc0, 0, 0, 0);
      acc1 = __builtin_amdgcn_mfma_f32_16x16x32_bf16(a1, bmain[t], acc1, 0, 0, 0);
    }
    #pragma unroll
    for (int tg = 0; tg < 3; ++tg){
      int sp0 = (h00 + tdh[tg])*26 + (w00 + tdw[tg]);
      int sp1 = (h01 + tdh[tg])*26 + (w01 + tdw[tg]);
      short8x a0 = *(const short8x*)&xin[sp0*40 + 32];
      short8x a1 = *(const short8x*)&xin[sp1*40 + 32];
      acc0 = __builtin_amdgcn_mfma_f32_16x16x32_bf16(a0, btail[tg], acc0, 0, 0, 0);
      acc1 = __builtin_amdgcn_mfma_f32_16x16x32_bf16(a1, btail[tg], acc1, 0, 0, 0);
    }
    if (n < 40){
      float s1 = acc0[0]+acc0[1]+acc0[2]+acc0[3] + acc1[0]+acc1[1]+acc1[2]+acc1[3];
      float s2 = acc0[0]*acc0[0]+acc0[1]*acc0[1]+acc0[2]*acc0[2]+acc0[3]*acc0[3]
               + acc1[0]*acc1[0]+acc1[1]*acc1[1]+acc1[2]*acc1[2]+acc1[3]*acc1[3];
      atomicAdd(&lsum[o], s1); atomicAdd(&lss[o], s2);
      float mx0 = fmaxf(fmaxf(acc0[0], acc0[1]), fmaxf(acc0[2], acc0[3]));
      float mx1 = fmaxf(fmaxf(acc1[0], acc1[1]), fmaxf(acc1[2], acc1[3]));
      size_t pbase = ((size_t)b*40 + n)*144;
      stv(ap2 + pbase + mt0*4 + lq, mx0);
      stv(ap2 + pbase + mt1*4 + lq, mx1);
    }
  }
  __syncthreads();
  if (tid < 10){ atomicAdd(&ssum[tid], lsum[tid]); atomicAdd(&ssq[tid], lss[tid]); }
}

// ---------------- generic GG conv via MFMA (L3/L4), tail-merged K ----------------
template<int HIN, int WIN, int NT, typename TI>
__global__ __launch_bounds__(NT) void k_conv_ggm(const TI* __restrict__ act,
                                                 const float* __restrict__ scale,
                                                 const float* __restrict__ shift,
                                                 const float* __restrict__ attm,
                                                 const short* __restrict__ btg,
                                                 float* __restrict__ out,
                                                 float* __restrict__ ssum, float* __restrict__ ssq){
  constexpr int HOUT = HIN - 2, WOUT = WIN - 2;
  constexpr int M = HOUT*WOUT, HW = HIN*WIN;
  constexpr int MT = (M + 15)/16, MU = (MT + 1)/2, UNITS = MU*3;
  constexpr int NWV = NT/64;
  __shared__ alignas(16) short xin[HW*40];
  __shared__ float lsum[16], lss[16];
  int tid = threadIdx.x, b = blockIdx.x;
  if (tid < 16){ lsum[tid] = 0.f; lss[tid] = 0.f; }
  for (int i = tid; i < HW*40; i += NT){
    int sp = i / 40, ch = i % 40;
    int ci = ch >> 2, s = ch & 3;
    float a = ldv(act + ((size_t)b*40 + ch)*HW + sp);
    a = fmaxf(fmaf(a, scale[ci], shift[ci]), 0.f);
    xin[i] = bfbits(a * attm[((size_t)b*4 + s)*HW + sp]);
  }
  __syncthreads();
  int wv = tid >> 6, lane = tid & 63, lm = lane & 15, lq = lane >> 4;
  short8x bmain[9], btail[3];
  int tdh[3], tdw[3];
  #pragma unroll
  for (int tg = 0; tg < 3; ++tg){
    int tap = tg*4 + lq; if (tap > 8) tap = 8;
    tdh[tg] = tap / 3; tdw[tg] = tap % 3;
  }
  int curNt = -1, n = 0, o = 0;
  for (int u = wv; u < UNITS; u += NWV){
    int nt = u / MU, mu = u % MU;
    if (nt != curNt){
      curNt = nt; n = nt*16 + lm; o = n >> 2;
      #pragma unroll
      for (int t = 0; t < 9; ++t)
        bmain[t] = *(const short8x*)(btg + (((t*4 + lq)*48 + n) << 3));
      #pragma unroll
      for (int tg = 0; tg < 3; ++tg)
        btail[tg] = *(const short8x*)(btg + 13824 + (((tg*4 + lq)*48 + n) << 3));
    }
    int mt0 = mu*2, mt1 = mu*2 + 1;
    int mA0 = mt0*16 + lm; if (mA0 > M-1) mA0 = M-1;
    int mA1 = mt1*16 + lm; if (mA1 > M-1) mA1 = M-1;
    int mh0 = mA0 / WOUT, mw0 = mA0 % WOUT;
    int mh1 = mA1 / WOUT, mw1 = mA1 % WOUT;
    f32x4 acc0 = {0.f,0.f,0.f,0.f}, acc1 = {0.f,0.f,0.f,0.f};
    #pragma unroll
    for (int t = 0; t < 9; ++t){
      int sp0 = (mh0 + t/3)*WIN + (mw0 + t%3);
      int sp1 = (mh1 + t/3)*WIN + (mw1 + t%3);
      short8x a0 = *(const short8x*)&xin[sp0*40 + lq*8];
      short8x a1 = *(const short8x*)&xin[sp1*40 + lq*8];
      acc0 = __builtin_amdgcn_mfma_f32_16x16x32_bf16(a0, bmain[t], acc0, 0, 0, 0);
      acc1 = __builtin_amdgcn_mfma_f32_16x16x32_bf16(a1, bmain[t], acc1, 0, 0, 0);
    }
    #pragma unroll
    for (int tg = 0; tg < 3; ++tg){
      int sp0 = (mh0 + tdh[tg])*WIN + (mw0 + tdw[tg]);
      int sp1 = (mh1 + tdh[tg])*WIN + (mw1 + tdw[tg]);
      short8x a0 = *(const short8x*)&xin[sp0*40 + 32];
      short8x a1 = *(const short8x*)&xin[sp1*40 + 32];
      acc0 = __builtin_amdgcn_mfma_f32_16x16x32_bf16(a0, btail[tg], acc0, 0, 0, 0);
      acc1 = __builtin_amdgcn_mfma_f32_16x16x32_bf16(a1, btail[tg], acc1, 0, 0, 0);
    }
    if (n < 40){
      float s1 = 0.f, s2 = 0.f;
      size_t obase = ((size_t)b*40 + n)*M;
      #pragma unroll
      for (int reg = 0; reg < 4; ++reg){
        int m0 = mt0*16 + lq*4 + reg;
        if (m0 < M){ float v = acc0[reg]; s1 += v; s2 += v*v; out[obase + m0] = v; }
        int m1 = mt1*16 + lq*4 + reg;
        if (m1 < M){ float v = acc1[reg]; s1 += v; s2 += v*v; out[obase + m1] = v; }
      }
      atomicAdd(&lsum[o], s1); atomicAdd(&lss[o], s2);
    }
  }
  __syncthreads();
  if (tid < 10){ atomicAdd(&ssum[tid], lsum[tid]); atomicAdd(&ssq[tid], lss[tid]); }
}

// ---------------- generic GG spatial attention (L3..L7) ----------------
template<int H, int W, int NT, typename TA>
__global__ __launch_bounds__(NT) void k_att_gg(const TA* __restrict__ act,
                                               const float* __restrict__ scale,
                                               const float* __restrict__ shift,
                                               const void* __restrict__ aw,
                                               const int* __restrict__ ctrl,
                                               float* __restrict__ att){
  constexpr int WG = (W + 6) | 1;
  constexpr int HW = H*W;
  __shared__ float ps[8*H*WG];
  __shared__ float wl[1568];
  int b = blockIdx.x, tid = threadIdx.x;
  int f32 = ctrl[0];
  for (int i = tid; i < 4*H*WG; i += NT){
    int s = i / (H*WG), rem = i % (H*WG), row = rem / WG, col = rem % WG;
    int cc = col - 3;
    float mn = 0.f, mx = 0.f;
    if (cc >= 0 && cc < W){
      float sum = 0.f; mx = 0.f;
      const TA* ap = act + (size_t)b*40*HW + (size_t)s*HW + row*W + cc;
      #pragma unroll
      for (int c = 0; c < 10; ++c){
        float v = fmaxf(fmaf(ldv(ap + (size_t)c*4*HW), scale[c], shift[c]), 0.f);
        sum += v; mx = fmaxf(mx, v);
      }
      mn = sum * 0.1f;
    }
    ps[s*H*WG + row*WG + col] = mn;
    ps[(4 + s)*H*WG + row*WG + col] = mx;
  }
  for (int i = tid; i < 1568; i += NT){
    int r = i / 392, rem = i % 392, i2 = rem / 196, s = (rem % 196)/49, t = rem % 49;
    int sp = (s - r) & 3;
    wl[i] = ldin(aw, (i2*4 + sp)*49 + rot_src<7>(r, t), f32);
  }
  __syncthreads();
  for (int it = tid; it < 4*H; it += NT){
    int r = it / H, h = it % H;
    float acc[W];
    #pragma unroll
    for (int w = 0; w < W; ++w) acc[w] = 0.f;
    for (int c = 0; c < 8; ++c){
      const float* wb = wl + r*392 + c*49;
      const float* pb = ps + c*H*WG;
      #pragma unroll
      for (int u = 0; u < 7; ++u){
        int row = h + u - 3;
        if (row < 0 || row >= H) continue;
        float rr[W + 6];
        #pragma unroll
        for (int j = 0; j < W + 6; ++j) rr[j] = pb[row*WG + j];
        #pragma unroll
        for (int v = 0; v < 7; ++v){
          float wv = wb[u*7 + v];
          #pragma unroll
          for (int w = 0; w < W; ++w) acc[w] = fmaf(rr[w + v], wv, acc[w]);
        }
      }
    }
    size_t base = ((size_t)b*4 + r)*HW + (size_t)h*W;
    #pragma unroll
    for (int w = 0; w < W; ++w) att[base + w] = sigm(acc[w]);
  }
}

// ---------------- fp32 GG conv (L5..L7) ----------------
template<int HIN, int WIN, int K, int SR, int NT, bool STATS, typename TI, typename TO>
__global__ __launch_bounds__(NT) void k_conv_gg(const TI* __restrict__ act,
                                                const float* __restrict__ scale,
                                                const float* __restrict__ shift,
                                                const float* __restrict__ attm,
                                                const void* __restrict__ cw,
                                                const int* __restrict__ ctrl,
                                                TO* __restrict__ out,
                                                float* __restrict__ ssum, float* __restrict__ ssq){
  constexpr int HOUT = HIN - K + 1;
  constexpr int WOUT = WIN - K + 1;
  constexpr int NS   = HOUT / SR;
  constexpr int WP   = WIN | 1;
  constexpr int NW   = 10*10*4*K*K;
  __shared__ float xin[40*HIN*WP];
  __shared__ float wl[NW];
  __shared__ float lsum[16], lss[16];
  int tid = threadIdx.x;
  int b = blockIdx.x;
  int f32 = ctrl[0];
  for (int i = tid; i < 40*HIN*WP; i += NT){
    int c = i / (HIN*WP), rem = i % (HIN*WP), rr = rem / WP, col = rem % WP;
    float v = 0.f;
    if (col < WIN){
      int ch = c >> 2, s = c & 3;
      float a = ldv(act + ((size_t)b*40 + c)*HIN*WIN + (size_t)rr*WIN + col);
      a = fmaxf(fmaf(a, scale[ch], shift[ch]), 0.f);
      v = a * attm[((size_t)b*4 + s)*HIN*WIN + (size_t)rr*WIN + col];
    }
    xin[i] = v;
  }
  for (int i = tid; i < NW; i += NT) wl[i] = ldin(cw, i, f32);
  if (STATS && tid < 16){ lsum[tid] = 0.f; lss[tid] = 0.f; }
  __syncthreads();
  for (int it = tid; it < 40*NS; it += NT){
    int o = it / (4*NS), rem = it % (4*NS), r = rem / NS, hs = rem % NS;
    int h0 = hs * SR;
    int perm[K*K];
    #pragma unroll
    for (int t = 0; t < K*K; ++t) perm[t] = rot_src<K>(r, t);
    float acc[SR][WOUT];
    #pragma unroll
    for (int a = 0; a < SR; ++a)
      #pragma unroll
      for (int w = 0; w < WOUT; ++w) acc[a][w] = 0.f;
    for (int ci = 0; ci < 10; ++ci){
      #pragma unroll
      for (int s = 0; s < 4; ++s){
        int sp = (s - r) & 3;
        const float* wb = wl + (size_t)((o*10 + ci)*4 + sp)*K*K;
        float wt[K*K];
        #pragma unroll
        for (int t = 0; t < K*K; ++t) wt[t] = wb[perm[t]];
        const float* ib = xin + (ci*4 + s)*HIN*WP;
        #pragma unroll
        for (int ri = 0; ri < SR + K - 1; ++ri){
          float rr[WP];
          #pragma unroll
          for (int j = 0; j < WP; ++j) rr[j] = ib[(h0 + ri)*WP + j];
          #pragma unroll
          for (int u = 0; u < K; ++u){
            int orr = ri - u;
            if (orr < 0 || orr >= SR) continue;
            #pragma unroll
            for (int v = 0; v < K; ++v){
              float wv = wt[u*K + v];
              #pragma unroll
              for (int w = 0; w < WOUT; ++w) acc[orr][w] = fmaf(rr[w + v], wv, acc[orr][w]);
            }
          }
        }
      }
    }
    if (STATS){
      float s1 = 0.f, s2 = 0.f;
      #pragma unroll
      for (int a = 0; a < SR; ++a)
        #pragma unroll
        for (int w = 0; w < WOUT; ++w){ s1 += acc[a][w]; s2 += acc[a][w]*acc[a][w]; }
      atomicAdd(&lsum[o], s1); atomicAdd(&lss[o], s2);
    }
    #pragma unroll
    for (int a = 0; a < SR; ++a){
      size_t base = ((size_t)b*40 + o*4 + r)*HOUT*WOUT + (size_t)(h0 + a)*WOUT;
      #pragma unroll
      for (int w = 0; w < WOUT; ++w) stv(out + base + w, acc[a][w]);
    }
  }
  if (STATS){
    __syncthreads();
    if (tid < 10){ atomicAdd(&ssum[tid], lsum[tid]); atomicAdd(&ssq[tid], lss[tid]); }
  }
}

// ---------------- group max over orientations, dual-dtype out ----------------
__global__ __launch_bounds__(256) void k_out_max(const float* __restrict__ y7, void* __restrict__ outp,
                                                 const int* __restrict__ ctrl){
  int idx = blockIdx.x * 256 + threadIdx.x;
  if (idx >= 20480) return;
  int f32 = ctrl[0];
  const float* p = y7 + (size_t)idx*4;
  float m = fmaxf(fmaxf(p[0], p[1]), fmaxf(p[2], p[3]));
  if (f32) ((float*)outp)[idx] = m;
  else stv((bf*)outp + idx, m);
}

extern "C" void kernel_launch(void* const* d_in, const int* in_sizes, int n_in,
                              void* d_out, int out_size, void* d_ws, size_t ws_size,
                              hipStream_t stream){
  (void)in_sizes; (void)n_in; (void)out_size; (void)ws_size;
  const void* x  = d_in[0];
  const void* c1 = d_in[1];
  const void* a1 = d_in[2];
  const void* c2 = d_in[3];
  const void* a2 = d_in[4];
  const void* c3 = d_in[5];
  const void* a3 = d_in[6];
  const void* c4 = d_in[7];
  const void* a4 = d_in[8];
  const void* c5 = d_in[9];
  const void* a5 = d_in[10];
  const void* c6 = d_in[11];
  const void* a6 = d_in[12];
  const void* c7 = d_in[13];
  const void* a7 = d_in[14];
  const void* bng[6] = {d_in[15],d_in[17],d_in[19],d_in[21],d_in[23],d_in[25]};
  const void* bnb[6] = {d_in[16],d_in[18],d_in[20],d_in[22],d_in[24],d_in[26]};

  // ---- arena ----
  size_t off = 0;
  char* wsb = (char*)d_ws;
  auto alloc = [&](size_t bytes)->void*{ void* p = wsb + off; off += (bytes + 255) & ~(size_t)255; return p; };
  int*   ctrl   = (int*)alloc(256);
  float* stats  = (float*)alloc(192*sizeof(float));
  float* scales = (float*)alloc(192*sizeof(float));
  short* btfr   = (short*)alloc(3*18432*2);               // tail-merged B-frag buffers
  char*  region1 = (char*)alloc(28573696);
  bf*    ap2 = (bf*)alloc((size_t)2048*40*144*2);
  float* yD  = (float*)alloc((size_t)2048*40*100*4);
  float* xa    = (float*)region1;
  float* attf2 = (float*)(region1 + 6422528);
  float* yE    = (float*)region1;
  float* attf3 = (float*)(region1 + 20971520);

  hipMemsetAsync(ctrl, 0, 1024, stream);
  k_detect<<<1, 64, 0, stream>>>(x, ctrl);
  k_build_bt<<<3, 256, 0, stream>>>(c2, c3, c4, ctrl, btfr);

  // L1
  k_l1<<<2048, 256, 0, stream>>>(x, a1, c1, ctrl, xa, stats + 0, stats + 16);
  k_finalize<<<1, 64, 0, stream>>>(stats + 0, stats + 16, bng[0], bnb[0], ctrl, 1.f/5537792.f, scales + 0, scales + 16);

  // L2
  k_att2<<<2048, 128, 0, stream>>>(xa, c1, scales + 0, scales + 16, a2, ctrl, attf2);
  k_conv2m<<<2048, 512, 0, stream>>>(xa, c1, scales + 0, scales + 16, attf2, btfr, ctrl, ap2, stats + 32, stats + 48);
  k_finalize<<<1, 64, 0, stream>>>(stats + 32, stats + 48, bng[1], bnb[1], ctrl, 1.f/4718592.f, scales + 32, scales + 48);

  // L3: 12->10 (MFMA)
  k_att_gg<12,12,64,bf><<<2048, 64, 0, stream>>>(ap2, scales + 32, scales + 48, a3, ctrl, attf3);
  k_conv_ggm<12,12,256,bf><<<2048, 256, 0, stream>>>(ap2, scales + 32, scales + 48,
                                                     attf3, btfr + 18432, yD, stats + 64, stats + 80);
  k_finalize<<<1, 64, 0, stream>>>(stats + 64, stats + 80, bng[2], bnb[2], ctrl, 1.f/819200.f, scales + 64, scales + 80);

  // L4: 10->8 (MFMA)
  k_att_gg<10,10,64,float><<<2048, 64, 0, stream>>>(yD, scales + 64, scales + 80, a4, ctrl, attf3);
  k_conv_ggm<10,10,128,float><<<2048, 128, 0, stream>>>(yD, scales + 64, scales + 80,
                                                        attf3, btfr + 36864, yE, stats + 96, stats + 112);
  k_finalize<<<1, 64, 0, stream>>>(stats + 96, stats + 112, bng[3], bnb[3], ctrl, 1.f/524288.f, scales + 96, scales + 112);

  // L5: 8->6 (fp32)
  k_att_gg<8,8,64,float><<<2048, 64, 0, stream>>>(yE, scales + 96, scales + 112, a5, ctrl, attf3);
  k_conv_gg<8,8,3,2,192,true,float,float><<<2048, 192, 0, stream>>>(yE, scales + 96, scales + 112,
                                                                attf3, c5, ctrl, yD, stats + 128, stats + 144);
  k_finalize<<<1, 64, 0, stream>>>(stats + 128, stats + 144, bng[4], bnb[4], ctrl, 1.f/294912.f, scales + 128, scales + 144);

  // L6: 6->4 (fp32)
  k_att_gg<6,6,64,float><<<2048, 64, 0, stream>>>(yD, scales + 128, scales + 144, a6, ctrl, attf3);
  k_conv_gg<6,6,3,2,128,true,float,float><<<2048, 128, 0, stream>>>(yD, scales + 128, scales + 144,
                                                                attf3, c6, ctrl, yE, stats + 160, stats + 176);
  k_finalize<<<1, 64, 0, stream>>>(stats + 160, stats + 176, bng[5], bnb[5], ctrl, 1.f/131072.f, scales + 160, scales + 176);

  // L7: 4x4 -> 1x1, no bn; then orientation max
  k_att_gg<4,4,64,float><<<2048, 64, 0, stream>>>(yE, scales + 160, scales + 176, a7, ctrl, attf3);
  k_conv_gg<4,4,4,1,64,false,float,float><<<2048, 64, 0, stream>>>(yE, scales + 160, scales + 176,
                                                                attf3, c7, ctrl, yD, (float*)nullptr, (float*)nullptr);
  k_out_max<<<80, 256, 0, stream>>>(yD, d_out, ctrl);
}